// Round 1
// baseline (370.086 us; speedup 1.0000x reference)
//
#include <hip/hip_runtime.h>
#include <hip/hip_bf16.h>

#define DEVI __device__ __forceinline__

typedef __attribute__((ext_vector_type(8))) short bf16x8;
typedef __attribute__((ext_vector_type(8))) unsigned short u16x8;
typedef __attribute__((ext_vector_type(4))) float f32x4;

static constexpr int BB = 16, CC = 512, NT = 784, HD = 8, DH = 32;
static constexpr int INNER = 256, HID = 2048, MTOT = BB * NT; // 12544

DEVI short f2bf(float x) {
  unsigned u = __builtin_bit_cast(unsigned, x);
  u += 0x7fffu + ((u >> 16) & 1u);
  return (short)(u >> 16);
}

DEVI void gll16(const void* g, void* l) {
  __builtin_amdgcn_global_load_lds(
      (const __attribute__((address_space(1))) unsigned int*)g,
      (__attribute__((address_space(3))) unsigned int*)l, 16, 0, 0);
}

// ---------------- weight cast+transpose: W[K0][N0] f32 -> WT[N0][K0] bf16 ----
__global__ void wprep_kernel(const float* __restrict__ W, short* __restrict__ WT,
                             int K0, int N0) {
  int id = blockIdx.x * 256 + threadIdx.x;
  int n = id / K0, k = id - n * K0;
  WT[id] = f2bf(W[(size_t)k * N0 + n]);
}

// ---------------- LayerNorm (block = 1 token, 256 thr, C=512) ----------------
template <bool STRIDED>
__global__ void ln_kernel(const float* __restrict__ in, const float* __restrict__ gw,
                          const float* __restrict__ bw, float* __restrict__ xs_out,
                          short* __restrict__ h_out) {
  int t = blockIdx.x;
  int tid = threadIdx.x;
  float v0, v1;
  if (STRIDED) {
    int b = t / NT, n = t - b * NT;
    const float* p = in + (size_t)b * CC * NT + n;
    v0 = p[(size_t)tid * NT];
    v1 = p[(size_t)(tid + 256) * NT];
  } else {
    const float* p = in + (size_t)t * CC;
    v0 = p[tid];
    v1 = p[tid + 256];
  }
  float s = v0 + v1, s2 = v0 * v0 + v1 * v1;
#pragma unroll
  for (int m = 1; m < 64; m <<= 1) {
    s += __shfl_xor(s, m);
    s2 += __shfl_xor(s2, m);
  }
  __shared__ float red[8];
  int wid = tid >> 6;
  if ((tid & 63) == 0) { red[wid] = s; red[4 + wid] = s2; }
  __syncthreads();
  s = red[0] + red[1] + red[2] + red[3];
  s2 = red[4] + red[5] + red[6] + red[7];
  float mu = s * (1.f / 512.f);
  float var = s2 * (1.f / 512.f) - mu * mu;
  float rs = rsqrtf(var + 1e-5f);
  if (xs_out) {
    xs_out[(size_t)t * CC + tid] = v0;
    xs_out[(size_t)t * CC + tid + 256] = v1;
  }
  h_out[(size_t)t * CC + tid] = f2bf((v0 - mu) * rs * gw[tid] + bw[tid]);
  h_out[(size_t)t * CC + tid + 256] = f2bf((v1 - mu) * rs * gw[tid + 256] + bw[tid + 256]);
}

// ---------------- GEMM: C[m][n] = sum_k A[m][k] * BT[n][k] ------------------
// EPI 0: qkv scatter (bf16 -> q/k/v [B,H,N,32]);  1: +bias +res -> f32;
// EPI 2: +bias, exact GELU -> bf16
template <int EPI>
__global__ __launch_bounds__(256, 2) void gemm_bt(
    const short* __restrict__ A, const short* __restrict__ BT,
    const float* __restrict__ bias, int K, void* __restrict__ out0,
    void* __restrict__ o1, void* __restrict__ o2, const float* __restrict__ res,
    int Nld) {
  __shared__ short As[128 * 64];
  __shared__ short Bs[128 * 64];
  const int tid = threadIdx.x;
  const int lane = tid & 63, wid = tid >> 6;
  const int m0 = blockIdx.x * 128, n0 = blockIdx.y * 128;
  const int wm = wid >> 1, wn = wid & 1;
  f32x4 acc[4][4] = {};
  for (int kt = 0; kt < K; kt += 64) {
#pragma unroll
    for (int call = 0; call < 4; ++call) {
      int cb = call * 256 + (wid << 6);
      int c = cb + lane;
      int row = c >> 3, j8 = c & 7;
      gll16(A + (size_t)(m0 + row) * K + kt + j8 * 8, &As[cb * 8]);
    }
#pragma unroll
    for (int call = 0; call < 4; ++call) {
      int cb = call * 256 + (wid << 6);
      int c = cb + lane;
      int row = c >> 3, j8 = c & 7;
      gll16(BT + (size_t)(n0 + row) * K + kt + j8 * 8, &Bs[cb * 8]);
    }
    __syncthreads();
#pragma unroll
    for (int kk = 0; kk < 64; kk += 32) {
      bf16x8 af[4], bfr[4];
#pragma unroll
      for (int mf = 0; mf < 4; ++mf)
        af[mf] = *(const bf16x8*)&As[(wm * 64 + mf * 16 + (lane & 15)) * 64 + kk + (lane >> 4) * 8];
#pragma unroll
      for (int nf = 0; nf < 4; ++nf)
        bfr[nf] = *(const bf16x8*)&Bs[(wn * 64 + nf * 16 + (lane & 15)) * 64 + kk + (lane >> 4) * 8];
#pragma unroll
      for (int mf = 0; mf < 4; ++mf)
#pragma unroll
        for (int nf = 0; nf < 4; ++nf)
          acc[mf][nf] = __builtin_amdgcn_mfma_f32_16x16x32_bf16(af[mf], bfr[nf], acc[mf][nf], 0, 0, 0);
    }
    __syncthreads();
  }
#pragma unroll
  for (int mf = 0; mf < 4; ++mf)
#pragma unroll
    for (int nf = 0; nf < 4; ++nf) {
      int col = n0 + wn * 64 + nf * 16 + (lane & 15);
      float bv = bias[col];
#pragma unroll
      for (int r = 0; r < 4; ++r) {
        int row = m0 + wm * 64 + mf * 16 + (lane >> 4) * 4 + r;
        float val = acc[mf][nf][r] + bv;
        if (EPI == 0) {
          int which = col >> 8, head = (col >> 5) & 7, dd = col & 31;
          int b = row / NT, n = row - b * NT;
          short* dst = (which == 0) ? (short*)out0 : (which == 1) ? (short*)o1 : (short*)o2;
          dst[((size_t)((b * HD + head) * NT + n)) * DH + dd] = f2bf(val);
        } else if (EPI == 1) {
          ((float*)out0)[(size_t)row * Nld + col] = val + res[(size_t)row * Nld + col];
        } else {
          float gl = 0.5f * val * (1.f + erff(val * 0.70710678118f));
          ((short*)out0)[(size_t)row * Nld + col] = f2bf(gl);
        }
      }
    }
}

// ---------------- V transpose: v[BH][N][32] -> vt[BH][32][N] ----------------
__global__ void vtrans_kernel(const short* __restrict__ v, short* __restrict__ vt) {
  int id = blockIdx.x * 256 + threadIdx.x;  // 128*32*784
  int bh = id / (DH * NT);
  int rem = id - bh * DH * NT;
  int d = rem / NT, j = rem - d * NT;
  vt[id] = v[((size_t)bh * NT + j) * DH + d];
}

// ---------------- attention: flash-style, 128 Q-rows / block ----------------
__global__ __launch_bounds__(256, 2) void attn_kernel(
    const short* __restrict__ qb, const short* __restrict__ kb,
    const short* __restrict__ vtg, const float* __restrict__ rel,
    short* __restrict__ ob) {
  const int qc = blockIdx.x;  // 0..6
  const int bh = blockIdx.y;  // 0..127
  const int b = bh >> 3, h = bh & 7;
  const int tid = threadIdx.x, lane = tid & 63, wid = tid >> 6;
  const int qbase = qc * 128;
  const float SCALE = 0.17677669529663687f;  // 32^-0.5

  __shared__ short Ks[128 * 40];    // K tile, rows padded to 40 bf16
  __shared__ short Vts[32 * 136];   // V^T tile, rows padded to 136 bf16
  __shared__ short Pl[4][32 * 136]; // per-wave P tile
  __shared__ float biasT[3025];

  for (int i = tid; i < 3025; i += 256) biasT[i] = rel[i * 8 + h];

  const short* qrow = qb + (size_t)bh * NT * DH;
  bf16x8 aq[2];
#pragma unroll
  for (int mr = 0; mr < 2; ++mr) {
    int r = qbase + wid * 32 + mr * 16 + (lane & 15);
    if (r > 783) r = 783;
    aq[mr] = *(const bf16x8*)(qrow + (size_t)r * DH + (lane >> 4) * 8);
  }
  int hi[2][4], wi_[2][4];
#pragma unroll
  for (int mr = 0; mr < 2; ++mr)
#pragma unroll
    for (int r = 0; r < 4; ++r) {
      int i = qbase + wid * 32 + mr * 16 + (lane >> 4) * 4 + r;
      if (i > 783) i = 783;
      hi[mr][r] = i / 28;
      wi_[mr][r] = i - hi[mr][r] * 28;
    }
  float m_run[2][4], l_run[2][4];
  f32x4 o_acc[2][2] = {};
#pragma unroll
  for (int mr = 0; mr < 2; ++mr)
#pragma unroll
    for (int r = 0; r < 4; ++r) { m_run[mr][r] = -3e38f; l_run[mr][r] = 0.f; }

  const short* kbase = kb + (size_t)bh * NT * DH;
  const short* vbase = vtg + (size_t)bh * DH * NT;

  for (int jt = 0; jt < NT; jt += 128) {
    // stage K tile [128][32] -> padded [128][40]
#pragma unroll
    for (int i = 0; i < 2; ++i) {
      int c = tid + i * 256;
      int row = c >> 2, q4 = c & 3;
      int gr = jt + row;
      if (gr > 783) gr = 783;
      *(u16x8*)&Ks[row * 40 + q4 * 8] =
          *(const u16x8*)(kbase + (size_t)gr * DH + q4 * 8);
    }
    // stage V^T tile [32][128] -> padded [32][136]
#pragma unroll
    for (int i = 0; i < 2; ++i) {
      int c = tid + i * 256;
      int d = c >> 4, j16 = c & 15;
      *(u16x8*)&Vts[d * 136 + j16 * 8] =
          *(const u16x8*)(vbase + (size_t)d * NT + jt + j16 * 8);
    }
    __syncthreads();

    // S = Q K^T
    f32x4 s[2][8];
    {
      bf16x8 bk[8];
#pragma unroll
      for (int nf = 0; nf < 8; ++nf)
        bk[nf] = *(const bf16x8*)&Ks[(nf * 16 + (lane & 15)) * 40 + (lane >> 4) * 8];
#pragma unroll
      for (int mr = 0; mr < 2; ++mr)
#pragma unroll
        for (int nf = 0; nf < 8; ++nf) {
          f32x4 z = {0.f, 0.f, 0.f, 0.f};
          s[mr][nf] = __builtin_amdgcn_mfma_f32_16x16x32_bf16(aq[mr], bk[nf], z, 0, 0, 0);
        }
    }
    // scale + rel-bias + col mask
#pragma unroll
    for (int nf = 0; nf < 8; ++nf) {
      int j = jt + nf * 16 + (lane & 15);
      int valid = (j < 784);
      int hj = 0, wj = 0;
      if (valid) { hj = j / 28; wj = j - hj * 28; }
#pragma unroll
      for (int mr = 0; mr < 2; ++mr)
#pragma unroll
        for (int r = 0; r < 4; ++r) {
          float sv;
          if (valid)
            sv = s[mr][nf][r] * SCALE + biasT[(hi[mr][r] - hj + 27) * 55 + (wi_[mr][r] - wj + 27)];
          else
            sv = -1e30f;
          s[mr][nf][r] = sv;
        }
    }
    // tile row-max (cols live in lanes 0-15 of each 16-lane group + 8 nf regs)
    float mt[2][4];
#pragma unroll
    for (int mr = 0; mr < 2; ++mr)
#pragma unroll
      for (int r = 0; r < 4; ++r) {
        float v = s[mr][0][r];
#pragma unroll
        for (int nf = 1; nf < 8; ++nf) v = fmaxf(v, s[mr][nf][r]);
        mt[mr][r] = v;
      }
#pragma unroll
    for (int msk = 1; msk < 16; msk <<= 1)
#pragma unroll
      for (int mr = 0; mr < 2; ++mr)
#pragma unroll
        for (int r = 0; r < 4; ++r)
          mt[mr][r] = fmaxf(mt[mr][r], __shfl_xor(mt[mr][r], msk));
    // online update
    float ts[2][4];
#pragma unroll
    for (int mr = 0; mr < 2; ++mr)
#pragma unroll
      for (int r = 0; r < 4; ++r) {
        float mn = fmaxf(m_run[mr][r], mt[mr][r]);
        float corr = __expf(m_run[mr][r] - mn);
        m_run[mr][r] = mn;
        l_run[mr][r] *= corr;
        o_acc[mr][0][r] *= corr;
        o_acc[mr][1][r] *= corr;
        ts[mr][r] = 0.f;
      }
#pragma unroll
    for (int nf = 0; nf < 8; ++nf)
#pragma unroll
      for (int mr = 0; mr < 2; ++mr)
#pragma unroll
        for (int r = 0; r < 4; ++r) {
          float p = __expf(s[mr][nf][r] - m_run[mr][r]);
          ts[mr][r] += p;
          Pl[wid][(mr * 16 + (lane >> 4) * 4 + r) * 136 + nf * 16 + (lane & 15)] = f2bf(p);
        }
#pragma unroll
    for (int msk = 1; msk < 16; msk <<= 1)
#pragma unroll
      for (int mr = 0; mr < 2; ++mr)
#pragma unroll
        for (int r = 0; r < 4; ++r) ts[mr][r] += __shfl_xor(ts[mr][r], msk);
#pragma unroll
    for (int mr = 0; mr < 2; ++mr)
#pragma unroll
      for (int r = 0; r < 4; ++r) l_run[mr][r] += ts[mr][r];

    // O += P V
#pragma unroll
    for (int kk = 0; kk < 4; ++kk) {
      bf16x8 ap[2], bv[2];
#pragma unroll
      for (int mr = 0; mr < 2; ++mr)
        ap[mr] = *(const bf16x8*)&Pl[wid][(mr * 16 + (lane & 15)) * 136 + kk * 32 + (lane >> 4) * 8];
#pragma unroll
      for (int dr = 0; dr < 2; ++dr)
        bv[dr] = *(const bf16x8*)&Vts[(dr * 16 + (lane & 15)) * 136 + kk * 32 + (lane >> 4) * 8];
#pragma unroll
      for (int mr = 0; mr < 2; ++mr)
#pragma unroll
        for (int dr = 0; dr < 2; ++dr)
          o_acc[mr][dr] = __builtin_amdgcn_mfma_f32_16x16x32_bf16(ap[mr], bv[dr], o_acc[mr][dr], 0, 0, 0);
    }
    __syncthreads();
  }
  // normalize + store o [B,N,256]
#pragma unroll
  for (int mr = 0; mr < 2; ++mr)
#pragma unroll
    for (int dr = 0; dr < 2; ++dr)
#pragma unroll
      for (int r = 0; r < 4; ++r) {
        int row = qbase + wid * 32 + mr * 16 + (lane >> 4) * 4 + r;
        if (row < 784) {
          float val = o_acc[mr][dr][r] / l_run[mr][r];
          ob[((size_t)(b * NT + row)) * INNER + h * DH + dr * 16 + (lane & 15)] = f2bf(val);
        }
      }
}

// ---------------- final transpose: y[B][N][C] -> out[B][C][N] ---------------
__global__ void otrans_kernel(const float* __restrict__ y, float* __restrict__ out) {
  int id = blockIdx.x * 256 + threadIdx.x;  // 16*512*784
  int b = id / (CC * NT);
  int rem = id - b * CC * NT;
  int c = rem / NT, n = rem - c * NT;
  out[id] = y[((size_t)(b * NT + n)) * CC + c];
}

// ---------------------------------------------------------------------------
extern "C" void kernel_launch(void* const* d_in, const int* in_sizes, int n_in,
                              void* d_out, int out_size, void* d_ws, size_t ws_size,
                              hipStream_t stream) {
  const float* x = (const float*)d_in[0];
  const float* ln1_g = (const float*)d_in[1];
  const float* ln1_b = (const float*)d_in[2];
  const float* qkv_w = (const float*)d_in[3];
  const float* qkv_b = (const float*)d_in[4];
  const float* out_w = (const float*)d_in[5];
  const float* out_b = (const float*)d_in[6];
  const float* rel_table = (const float*)d_in[7];
  const float* ln2_g = (const float*)d_in[8];
  const float* ln2_b = (const float*)d_in[9];
  const float* ff_w1 = (const float*)d_in[10];
  const float* ff_b1 = (const float*)d_in[11];
  const float* ff_w2 = (const float*)d_in[12];
  const float* ff_b2 = (const float*)d_in[13];
  float* out = (float*)d_out;
  char* ws = (char*)d_ws;

  constexpr size_t OFF_XS = 0;                          // f32 [12544][512], later reused as y
  constexpr size_t OFF_H = 25690112;                    // bf16 [12544][512] (h1, later h2)
  constexpr size_t OFF_WQKV = 38535168;                 // bf16 [768][512]
  constexpr size_t OFF_WOUT = 39321600;                 // bf16 [512][256]
  constexpr size_t OFF_WF1 = 39583744;                  // bf16 [2048][512]
  constexpr size_t OFF_WF2 = 41680896;                  // bf16 [512][2048]
  constexpr size_t OFF_Q = 43778048;                    // bf16 [128][784][32]
  constexpr size_t OFF_K = 50200576;
  constexpr size_t OFF_V = 56623104;
  constexpr size_t OFF_VT = 63045632;                   // bf16 [128][32][784]
  constexpr size_t OFF_O = 69468160;                    // bf16 [12544][256]
  constexpr size_t OFF_XS2 = 75890688;                  // f32 [12544][512]
  constexpr size_t OFF_G = 101580800;                   // bf16 [12544][2048]

  float* xs = (float*)(ws + OFF_XS);
  short* h = (short*)(ws + OFF_H);
  short* wqkvT = (short*)(ws + OFF_WQKV);
  short* woutT = (short*)(ws + OFF_WOUT);
  short* wf1T = (short*)(ws + OFF_WF1);
  short* wf2T = (short*)(ws + OFF_WF2);
  short* qb = (short*)(ws + OFF_Q);
  short* kb = (short*)(ws + OFF_K);
  short* vb = (short*)(ws + OFF_V);
  short* vt = (short*)(ws + OFF_VT);
  short* ob = (short*)(ws + OFF_O);
  float* xs2 = (float*)(ws + OFF_XS2);
  short* g = (short*)(ws + OFF_G);
  float* y = (float*)(ws + OFF_XS);  // alias: xs dead after out-proj

  // weight prep
  wprep_kernel<<<1536, 256, 0, stream>>>(qkv_w, wqkvT, 512, 768);
  wprep_kernel<<<512, 256, 0, stream>>>(out_w, woutT, 256, 512);
  wprep_kernel<<<4096, 256, 0, stream>>>(ff_w1, wf1T, 512, 2048);
  wprep_kernel<<<4096, 256, 0, stream>>>(ff_w2, wf2T, 2048, 512);

  // LN1 (fused transpose), writes xs (residual) + h1 bf16
  ln_kernel<true><<<MTOT, 256, 0, stream>>>(x, ln1_g, ln1_b, xs, h);

  // QKV
  gemm_bt<0><<<dim3(98, 6), 256, 0, stream>>>(h, wqkvT, qkv_b, 512, qb, kb, vb, nullptr, 0);

  // V transpose
  vtrans_kernel<<<12544, 256, 0, stream>>>(vb, vt);

  // attention
  attn_kernel<<<dim3(7, 128), 256, 0, stream>>>(qb, kb, vt, rel_table, ob);

  // out-proj + residual -> xs2
  gemm_bt<1><<<dim3(98, 4), 256, 0, stream>>>(ob, woutT, out_b, 256, xs2, nullptr, nullptr, xs, 512);

  // LN2 -> h2
  ln_kernel<false><<<MTOT, 256, 0, stream>>>(xs2, ln2_g, ln2_b, nullptr, h);

  // FFN1 + GELU -> g
  gemm_bt<2><<<dim3(98, 16), 256, 0, stream>>>(h, wf1T, ff_b1, 512, g, nullptr, nullptr, nullptr, 2048);

  // FFN2 + residual -> y
  gemm_bt<1><<<dim3(98, 4), 256, 0, stream>>>(g, wf2T, ff_b2, 2048, y, nullptr, nullptr, xs2, 512);

  // final transpose
  otrans_kernel<<<25088, 256, 0, stream>>>(y, out);
}